// Round 3
// baseline (1024.733 us; speedup 1.0000x reference)
//
#include <hip/hip_runtime.h>
#include <cstdint>
#include <cstddef>

#define N_NODES 50000
#define N_EDGES 800000
#define D 128
#define DE 16
#define NBLK 196   // ceil(50000/256)

typedef float v2f __attribute__((ext_vector_type(2)));

// ---------------------------------------------------------------------------
// CSR build (dst-sorted, graph j=2, shared by both layers)
// ---------------------------------------------------------------------------
__global__ void csr_hist(const int* __restrict__ dst, int* __restrict__ count){
  int e = blockIdx.x*256 + threadIdx.x;
  if (e < N_EDGES) atomicAdd(&count[dst[e]], 1);
}

__global__ __launch_bounds__(256) void csr_blocksum(const int* __restrict__ count,
                                                    int* __restrict__ bsum){
  __shared__ int red[4];
  int i = blockIdx.x*256 + threadIdx.x;
  int v = (i < N_NODES) ? count[i] : 0;
  #pragma unroll
  for (int off=32; off; off>>=1) v += __shfl_down(v, off);
  if ((threadIdx.x & 63) == 0) red[threadIdx.x>>6] = v;
  __syncthreads();
  if (threadIdx.x == 0) bsum[blockIdx.x] = red[0]+red[1]+red[2]+red[3];
}

__global__ __launch_bounds__(256) void csr_scan_bsum(const int* __restrict__ bsum,
                                                     int* __restrict__ boff){
  __shared__ int s[256];
  int t = threadIdx.x;
  int v = (t < NBLK) ? bsum[t] : 0;
  s[t] = v; __syncthreads();
  for (int off=1; off<256; off<<=1){
    int u = (t >= off) ? s[t-off] : 0;
    __syncthreads(); s[t] += u; __syncthreads();
  }
  if (t < NBLK) boff[t] = s[t] - v;   // exclusive
}

__global__ __launch_bounds__(256) void csr_downsweep(const int* __restrict__ count,
    const int* __restrict__ boff, int* __restrict__ row_start, int* __restrict__ cursor){
  __shared__ int s[256];
  int t = threadIdx.x;
  int i = blockIdx.x*256 + t;
  int v = (i < N_NODES) ? count[i] : 0;
  s[t] = v; __syncthreads();
  for (int off=1; off<256; off<<=1){
    int u = (t >= off) ? s[t-off] : 0;
    __syncthreads(); s[t] += u; __syncthreads();
  }
  int excl = boff[blockIdx.x] + s[t] - v;
  if (i <= N_NODES) row_start[i] = excl;
  if (i <  N_NODES) cursor[i]   = excl;
}

__global__ void csr_scatter(const int* __restrict__ src, const int* __restrict__ dst,
                            int* __restrict__ cursor, int* __restrict__ perm,
                            int* __restrict__ src_perm){
  int e = blockIdx.x*256 + threadIdx.x;
  if (e >= N_EDGES) return;
  int d = dst[e];
  int pos = atomicAdd(&cursor[d], 1);
  perm[pos] = e;
  src_perm[pos] = src[e];
}

// ---------------------------------------------------------------------------
// LSTM: P[t][r] = Wih[r] . x[t] + (bih[r]+bhh[r])   (wide, parallel)
// Natural gate-major row order r = q*128 + j.
// ---------------------------------------------------------------------------
__global__ __launch_bounds__(512) void lstm_pre(const float* __restrict__ Wih,
     const float* __restrict__ bih, const float* __restrict__ bhh,
     const float* __restrict__ xin, float* __restrict__ P){
  __shared__ float xs[128];
  int i = blockIdx.x >> 7, t = blockIdx.x & 127;
  const float* x = xin + (size_t)i*16384;
  if (threadIdx.x < 128) xs[threadIdx.x] = x[t*128 + threadIdx.x];
  __syncthreads();
  int r = threadIdx.x;
  const float4* wr = (const float4*)(Wih + (size_t)(i*512 + r)*128);
  const float4* x4 = (const float4*)xs;
  float acc = bih[i*512+r] + bhh[i*512+r];
  #pragma unroll
  for (int k=0;k<32;k++){
    float4 w = wr[k]; float4 xv = x4[k];
    acc += w.x*xv.x + w.y*xv.y + w.z*xv.z + w.w*xv.w;
  }
  P[(size_t)(i*128+t)*512 + r] = acc;
}

// Recurrent scan, K-SPLIT layout + packed-FP32 FMA + transposed partials.
// 512 threads = 8 waves. Wave w: kc = w>>1 owns K-chunk [kc*32,+32);
// rh = w&1 owns row half. Lane l: 4 rows row0 = rh*256 + l*4 + {0..3};
// weights 4 rows x 16 v2f = 128 VGPRs (lives in unified VGPR/AGPR file).
// Per step:
//   FMA phase: 8 broadcast ds_read_b128 of this wave's 32 h values into regs,
//     then 64 v_pk_fma_f32 (128 MAC) -> issue floor ~256 cyc/CU (was 512).
//     Partials stored TRANSPOSED part[row][kc]: 4 ds_write_b32, 2-way
//     bank-aliased only (free per m136).
//   B1; threads j<128: 4 ds_read_b128 (part[q*128+j][0..3]) -> gate sums,
//     nonlinearities, register-resident c, write hs[j]; B2.
//   xout store issued AFTER B2 so it drains under next FMA phase.
__global__ __launch_bounds__(512, 2) void lstm_scan(const float* __restrict__ Whh,
     const float* __restrict__ P, float* __restrict__ xout){
  __shared__ float hs[128];
  __shared__ float part[512][4];
  const int i  = blockIdx.x;
  const int r  = threadIdx.x;
  const int w  = r >> 6;
  const int l  = r & 63;
  const int kc = w >> 1;               // K-chunk id
  const int rh = w & 1;                // row half
  const int row0 = rh*256 + l*4;       // 4 consecutive rows
  v2f wv[4][16];
  {
    const float* base = Whh + (size_t)i*512*128 + (size_t)row0*128 + kc*32;
    #pragma unroll
    for (int ri=0; ri<4; ri++){
      const v2f* p2 = (const v2f*)(base + ri*128);
      #pragma unroll
      for (int j=0;j<16;j++) wv[ri][j] = p2[j];
    }
  }
  float c = 0.f;
  float hreg = 0.f;
  if (r < 128) hs[r] = 0.f;
  __syncthreads();
  const float* Pi = P + (size_t)i*128*512;
  float* xo = xout + (size_t)i*128*128;
  for (int t=0; t<128; t++){
    // prefetch P for the serial phase (waves 0-1 only); consumed after B1
    float p0=0.f, p1=0.f, p2=0.f, p3=0.f;
    if (r < 128){
      p0 = Pi[t*512 +   0 + r];
      p1 = Pi[t*512 + 128 + r];
      p2 = Pi[t*512 + 256 + r];
      p3 = Pi[t*512 + 384 + r];
    }
    // FMA phase: broadcast-read this wave's 32 h values into registers
    float4 hbuf[8];
    {
      const float4* h4 = ((const float4*)hs) + kc*8;
      #pragma unroll
      for (int j=0;j<8;j++) hbuf[j] = h4[j];
    }
    const v2f* h2 = (const v2f*)hbuf;
    v2f a0 = (v2f)(0.f), a1 = (v2f)(0.f), a2 = (v2f)(0.f), a3 = (v2f)(0.f);
    #pragma unroll
    for (int j=0;j<16;j++){
      v2f hv = h2[j];
      a0 = __builtin_elementwise_fma(wv[0][j], hv, a0);
      a1 = __builtin_elementwise_fma(wv[1][j], hv, a1);
      a2 = __builtin_elementwise_fma(wv[2][j], hv, a2);
      a3 = __builtin_elementwise_fma(wv[3][j], hv, a3);
    }
    part[row0+0][kc] = a0.x + a0.y;
    part[row0+1][kc] = a1.x + a1.y;
    part[row0+2][kc] = a2.x + a2.y;
    part[row0+3][kc] = a3.x + a3.y;
    __syncthreads();                     // B1
    if (r < 128){
      float4 q0 = *(const float4*)part[      r];
      float4 q1 = *(const float4*)part[128 + r];
      float4 q2 = *(const float4*)part[256 + r];
      float4 q3 = *(const float4*)part[384 + r];
      float s0 = ((q0.x+q0.y) + (q0.z+q0.w)) + p0;
      float s1 = ((q1.x+q1.y) + (q1.z+q1.w)) + p1;
      float s2 = ((q2.x+q2.y) + (q2.z+q2.w)) + p2;
      float s3 = ((q3.x+q3.y) + (q3.z+q3.w)) + p3;
      float gi = __builtin_amdgcn_rcpf(1.f + __expf(-s0));
      float gf = __builtin_amdgcn_rcpf(1.f + __expf(-s1));
      float xg = fminf(fmaxf(s2, -15.f), 15.f);
      float eg = __expf(2.f*xg);
      float gg = (eg - 1.f) * __builtin_amdgcn_rcpf(eg + 1.f);
      float go = __builtin_amdgcn_rcpf(1.f + __expf(-s3));
      c = gf*c + gi*gg;
      float xc = fminf(fmaxf(c, -15.f), 15.f);
      float e2 = __expf(2.f*xc);
      float th = (e2 - 1.f) * __builtin_amdgcn_rcpf(e2 + 1.f);
      hreg = go*th;
      hs[r] = hreg;
    }
    __syncthreads();                     // B2
    if (r < 128) xo[t*128 + r] = hreg;   // store drains under next FMA phase
  }
}

// ---------------------------------------------------------------------------
// GAT stage A: ft = f @ W (50000x128 @ 128x128, fp32) + s_src = f @ a_src
// Inner product uses packed-FP32 fma (v_pk_fma_f32) via float2 ext-vectors.
// ---------------------------------------------------------------------------
__global__ __launch_bounds__(256) void gat_transform(const float* __restrict__ f,
    const float* __restrict__ W, const float* __restrict__ aw,
    float* __restrict__ ft, float* __restrict__ s_src){
  __shared__ float Ws[64*128];
  __shared__ float fs[128*36];
  int n0 = blockIdx.x * 32;
  {
    int n = threadIdx.x >> 3, kq = threadIdx.x & 7;
    int gn = n0 + n;
    #pragma unroll
    for (int p=0;p<4;p++){
      int k = kq*16 + p*4;
      float4 v = make_float4(0.f,0.f,0.f,0.f);
      if (gn < N_NODES) v = *(const float4*)(f + (size_t)gn*128 + k);
      fs[(k+0)*36+n] = v.x; fs[(k+1)*36+n] = v.y;
      fs[(k+2)*36+n] = v.z; fs[(k+3)*36+n] = v.w;
    }
  }
  int jg = threadIdx.x & 31, ng = threadIdx.x >> 5;
  v2f A00=(v2f)(0.f), A01=A00, A10=A00, A11=A00;
  v2f A20=A00, A21=A00, A30=A00, A31=A00;
  for (int kk=0; kk<128; kk+=64){
    __syncthreads();
    {
      const float4* W4 = (const float4*)(W + (size_t)kk*128);
      float4* Ws4w = (float4*)Ws;
      for (int idx = threadIdx.x; idx < 2048; idx += 256) Ws4w[idx] = W4[idx];
    }
    __syncthreads();
    const float4* Ws4 = (const float4*)Ws;
    #pragma unroll 4
    for (int k2=0;k2<64;k2++){
      float4 wvv = Ws4[k2*32 + jg];
      v2f wl; wl.x = wvv.x; wl.y = wvv.y;
      v2f wh; wh.x = wvv.z; wh.y = wvv.w;
      float4 fv = *(const float4*)&fs[(kk+k2)*36 + (ng<<2)];
      v2f f0 = (v2f)(fv.x), f1 = (v2f)(fv.y), f2 = (v2f)(fv.z), f3 = (v2f)(fv.w);
      A00 = __builtin_elementwise_fma(wl, f0, A00);
      A01 = __builtin_elementwise_fma(wh, f0, A01);
      A10 = __builtin_elementwise_fma(wl, f1, A10);
      A11 = __builtin_elementwise_fma(wh, f1, A11);
      A20 = __builtin_elementwise_fma(wl, f2, A20);
      A21 = __builtin_elementwise_fma(wh, f2, A21);
      A30 = __builtin_elementwise_fma(wl, f3, A30);
      A31 = __builtin_elementwise_fma(wh, f3, A31);
    }
  }
  int nb = n0 + (ng<<2);
  float4 o0; o0.x=A00.x; o0.y=A00.y; o0.z=A01.x; o0.w=A01.y;
  float4 o1; o1.x=A10.x; o1.y=A10.y; o1.z=A11.x; o1.w=A11.y;
  float4 o2; o2.x=A20.x; o2.y=A20.y; o2.z=A21.x; o2.w=A21.y;
  float4 o3; o3.x=A30.x; o3.y=A30.y; o3.z=A31.x; o3.w=A31.y;
  if (nb+0 < N_NODES) *(float4*)(ft + (size_t)(nb+0)*128 + (jg<<2)) = o0;
  if (nb+1 < N_NODES) *(float4*)(ft + (size_t)(nb+1)*128 + (jg<<2)) = o1;
  if (nb+2 < N_NODES) *(float4*)(ft + (size_t)(nb+2)*128 + (jg<<2)) = o2;
  if (nb+3 < N_NODES) *(float4*)(ft + (size_t)(nb+3)*128 + (jg<<2)) = o3;
  if (threadIdx.x < 32){
    int gn = n0 + threadIdx.x;
    if (gn < N_NODES){
      float s = 0.f;
      for (int k=0;k<128;k++) s += fs[k*36 + threadIdx.x] * aw[k];
      s_src[gn] = s;
    }
  }
}

// ---------------------------------------------------------------------------
// GAT stage B: score[p] = s_src[src_perm[p]] + ef[perm[p]] . a_edge
// ---------------------------------------------------------------------------
__global__ __launch_bounds__(256) void gat_edge_score(const int* __restrict__ perm,
    const int* __restrict__ src_perm, const float* __restrict__ s_src,
    const float* __restrict__ ef, const float* __restrict__ aw,
    float* __restrict__ score){
  int p = blockIdx.x*256 + threadIdx.x;
  if (p >= N_EDGES) return;
  int e = perm[p];
  int s = src_perm[p];
  const float4* A = (const float4*)(aw + 128);
  float4 A0=A[0], A1=A[1], A2=A[2], A3=A[3];
  const float4* ev = (const float4*)(ef + (size_t)e*16);
  float4 v0=ev[0], v1=ev[1], v2=ev[2], v3=ev[3];
  float acc = s_src[s];
  acc += v0.x*A0.x + v0.y*A0.y + v0.z*A0.z + v0.w*A0.w;
  acc += v1.x*A1.x + v1.y*A1.y + v1.z*A1.z + v1.w*A1.w;
  acc += v2.x*A2.x + v2.y*A2.y + v2.z*A2.z + v2.w*A2.w;
  acc += v3.x*A3.x + v3.y*A3.y + v3.z*A3.z + v3.w*A3.w;
  score[p] = acc;
}

// ---------------------------------------------------------------------------
// GAT stage C: per-node softmax + alpha-weighted gather + leaky_relu
// Pass 2 stores exp(score-m) back into score (each p owned by exactly one
// lane of one node-wave -> no hazard), so the serial pass-3 loop is a
// multiply instead of an __expf on the dependency chain.
// ---------------------------------------------------------------------------
__global__ __launch_bounds__(256) void gat_aggregate(const int* __restrict__ row_start,
    const int* __restrict__ src_perm, float* __restrict__ score,
    const float* __restrict__ ft, float* __restrict__ out){
  int lane = threadIdx.x & 63;
  int wv = threadIdx.x >> 6;
  int n = blockIdx.x*4 + wv;
  if (n >= N_NODES) return;
  int s = row_start[n], e = row_start[n+1];
  float m = -1e30f;
  for (int p = s+lane; p < e; p += 64) m = fmaxf(m, score[p]);
  #pragma unroll
  for (int off=32; off; off>>=1) m = fmaxf(m, __shfl_xor(m, off));
  float den = 0.f;
  for (int p = s+lane; p < e; p += 64){
    float ex = __expf(score[p]-m);
    den += ex;
    score[p] = ex;
  }
  #pragma unroll
  for (int off=32; off; off>>=1) den += __shfl_xor(den, off);
  float inv = (den > 0.f) ? 1.f/den : 0.f;
  float a0 = 0.f, a1 = 0.f;
  for (int p = s; p < e; p++){
    float al = score[p]*inv;
    int sp = src_perm[p];
    float2 v = ((const float2*)(ft + (size_t)sp*128))[lane];
    a0 += al*v.x; a1 += al*v.y;
  }
  float2 o;
  o.x = (a0 > 0.f) ? a0 : 0.01f*a0;
  o.y = (a1 > 0.f) ? a1 : 0.01f*a1;
  ((float2*)(out + (size_t)n*128))[lane] = o;
}

// ---------------------------------------------------------------------------
extern "C" void kernel_launch(void* const* d_in, const int* in_sizes, int n_in,
                              void* d_out, int out_size, void* d_ws, size_t ws_size,
                              hipStream_t stream){
  (void)in_sizes; (void)n_in; (void)out_size; (void)ws_size;
  const int*   src     = (const int*)d_in[0] + (size_t)2*N_EDGES;       // j=2 slice
  const int*   dst     = (const int*)d_in[1] + (size_t)2*N_EDGES;
  const float* n_feats = (const float*)d_in[2] + (size_t)2*N_NODES*D;
  const float* e_feats = (const float*)d_in[3] + (size_t)2*N_EDGES*DE;
  const float* W0      = (const float*)d_in[4];
  const float* Wih     = (const float*)d_in[5];
  const float* Whh     = (const float*)d_in[6];
  const float* bih     = (const float*)d_in[7];
  const float* bhh     = (const float*)d_in[8];
  const float* a_w     = (const float*)d_in[9];
  float* out = (float*)d_out;

  char* wsp = (char*)d_ws;
  auto alloc = [&](size_t bytes)->char*{
    char* p = wsp; wsp += (bytes + 255) & ~(size_t)255; return p;
  };
  float* P         = (float*)alloc((size_t)2*128*512*4);
  float* xA        = (float*)alloc((size_t)2*128*128*4);
  float* xB        = (float*)alloc((size_t)2*128*128*4);
  int*   count     = (int*)  alloc((size_t)N_NODES*4);
  int*   bsum      = (int*)  alloc((size_t)NBLK*4);
  int*   boff      = (int*)  alloc((size_t)NBLK*4);
  int*   row_start = (int*)  alloc((size_t)(N_NODES+1)*4);
  int*   cursor    = (int*)  alloc((size_t)N_NODES*4);
  int*   perm      = (int*)  alloc((size_t)N_EDGES*4);
  int*   src_perm  = (int*)  alloc((size_t)N_EDGES*4);
  float* score     = (float*)alloc((size_t)N_EDGES*4);
  float* s_src     = (float*)alloc((size_t)N_NODES*4);
  float* ft        = (float*)alloc((size_t)N_NODES*D*4);
  float* f1        = (float*)alloc((size_t)N_NODES*D*4);

  // CSR build (once; same graph for both layers)
  hipMemsetAsync(count, 0, (size_t)N_NODES*4, stream);
  csr_hist     <<<(N_EDGES+255)/256, 256, 0, stream>>>(dst, count);
  csr_blocksum <<<NBLK, 256, 0, stream>>>(count, bsum);
  csr_scan_bsum<<<1,    256, 0, stream>>>(bsum, boff);
  csr_downsweep<<<NBLK, 256, 0, stream>>>(count, boff, row_start, cursor);
  csr_scatter  <<<(N_EDGES+255)/256, 256, 0, stream>>>(src, dst, cursor, perm, src_perm);

  // LSTM: 3 applications, both layers batched per launch; final W lands in xA
  const float* xi = W0;
  float* xo = xA;
  for (int app=0; app<3; app++){
    lstm_pre <<<256, 512, 0, stream>>>(Wih, bih, bhh, xi, P);
    lstm_scan<<<2,   512, 0, stream>>>(Whh, P, xo);
    xi = xo;
    xo = (app==0) ? xB : xA;
  }
  const float* Wfin = xA;   // app0->xA, app1->xB, app2->xA

  // Two GAT layers on graph j=2 (feats[0],feats[1] are dead w.r.t. output)
  const float* fin = n_feats;
  for (int l=0; l<2; l++){
    float* outl = (l==0) ? f1 : out;
    gat_transform <<<(N_NODES+31)/32, 256, 0, stream>>>(fin, Wfin + (size_t)l*16384,
                                                        a_w + (size_t)l*272, ft, s_src);
    gat_edge_score<<<(N_EDGES+255)/256, 256, 0, stream>>>(perm, src_perm, s_src,
                                                          e_feats, a_w + (size_t)l*272, score);
    gat_aggregate <<<N_NODES/4, 256, 0, stream>>>(row_start, src_perm, score, ft, outl);
    fin = f1;
  }
}

// Round 4
// 930.517 us; speedup vs baseline: 1.1013x; 1.1013x over previous
//
#include <hip/hip_runtime.h>
#include <cstdint>
#include <cstddef>

#define N_NODES 50000
#define N_EDGES 800000
#define D 128
#define DE 16
#define NBLK 196   // ceil(50000/256)

typedef float v2f __attribute__((ext_vector_type(2)));

// ---------------------------------------------------------------------------
// CSR build (dst-sorted, graph j=2, shared by both layers)
// ---------------------------------------------------------------------------
__global__ void csr_hist(const int* __restrict__ dst, int* __restrict__ count){
  int e = blockIdx.x*256 + threadIdx.x;
  if (e < N_EDGES) atomicAdd(&count[dst[e]], 1);
}

__global__ __launch_bounds__(256) void csr_blocksum(const int* __restrict__ count,
                                                    int* __restrict__ bsum){
  __shared__ int red[4];
  int i = blockIdx.x*256 + threadIdx.x;
  int v = (i < N_NODES) ? count[i] : 0;
  #pragma unroll
  for (int off=32; off; off>>=1) v += __shfl_down(v, off);
  if ((threadIdx.x & 63) == 0) red[threadIdx.x>>6] = v;
  __syncthreads();
  if (threadIdx.x == 0) bsum[blockIdx.x] = red[0]+red[1]+red[2]+red[3];
}

__global__ __launch_bounds__(256) void csr_scan_bsum(const int* __restrict__ bsum,
                                                     int* __restrict__ boff){
  __shared__ int s[256];
  int t = threadIdx.x;
  int v = (t < NBLK) ? bsum[t] : 0;
  s[t] = v; __syncthreads();
  for (int off=1; off<256; off<<=1){
    int u = (t >= off) ? s[t-off] : 0;
    __syncthreads(); s[t] += u; __syncthreads();
  }
  if (t < NBLK) boff[t] = s[t] - v;   // exclusive
}

__global__ __launch_bounds__(256) void csr_downsweep(const int* __restrict__ count,
    const int* __restrict__ boff, int* __restrict__ row_start, int* __restrict__ cursor){
  __shared__ int s[256];
  int t = threadIdx.x;
  int i = blockIdx.x*256 + t;
  int v = (i < N_NODES) ? count[i] : 0;
  s[t] = v; __syncthreads();
  for (int off=1; off<256; off<<=1){
    int u = (t >= off) ? s[t-off] : 0;
    __syncthreads(); s[t] += u; __syncthreads();
  }
  int excl = boff[blockIdx.x] + s[t] - v;
  if (i <= N_NODES) row_start[i] = excl;
  if (i <  N_NODES) cursor[i]   = excl;
}

__global__ void csr_scatter(const int* __restrict__ src, const int* __restrict__ dst,
                            int* __restrict__ cursor, int* __restrict__ perm,
                            int* __restrict__ src_perm){
  int e = blockIdx.x*256 + threadIdx.x;
  if (e >= N_EDGES) return;
  int d = dst[e];
  int pos = atomicAdd(&cursor[d], 1);
  perm[pos] = e;
  src_perm[pos] = src[e];
}

// ---------------------------------------------------------------------------
// LSTM: P[t][r] = Wih[r] . x[t] + (bih[r]+bhh[r])   (wide, parallel)
// Natural gate-major row order r = q*128 + j.
// ---------------------------------------------------------------------------
__global__ __launch_bounds__(512) void lstm_pre(const float* __restrict__ Wih,
     const float* __restrict__ bih, const float* __restrict__ bhh,
     const float* __restrict__ xin, float* __restrict__ P){
  __shared__ float xs[128];
  int i = blockIdx.x >> 7, t = blockIdx.x & 127;
  const float* x = xin + (size_t)i*16384;
  if (threadIdx.x < 128) xs[threadIdx.x] = x[t*128 + threadIdx.x];
  __syncthreads();
  int r = threadIdx.x;
  const float4* wr = (const float4*)(Wih + (size_t)(i*512 + r)*128);
  const float4* x4 = (const float4*)xs;
  float acc = bih[i*512+r] + bhh[i*512+r];
  #pragma unroll
  for (int k=0;k<32;k++){
    float4 w = wr[k]; float4 xv = x4[k];
    acc += w.x*xv.x + w.y*xv.y + w.z*xv.z + w.w*xv.w;
  }
  P[(size_t)(i*128+t)*512 + r] = acc;
}

// Recurrent scan, K-SPLIT layout + packed-FP32 FMA, CONFLICT-FREE partials.
// 512 threads = 8 waves. Wave w: kc = w>>1 owns K-chunk [kc*32,+32);
// rh = w&1 owns row half. Lane l: 4 rows row0 = rh*256 + l*4 + {0..3};
// weights 4 rows x 16 v2f = 128 VGPRs (unified VGPR/AGPR file).
// Per step:
//   FMA phase: 8 broadcast ds_read_b128 of this wave's 32 h values into regs,
//     then 64 v_pk_fma_f32 (128 MAC) -> issue floor ~256 cyc/CU (was 512
//     scalar). Partials written to part[4][512] via ONE ds_write_b128 at
//     lane-stride 16B — canonical conflict-free pattern (round-2 measured
//     SQ_LDS_BANK_CONFLICT = 0; round-3 transposed layout measured 245760 —
//     reverted).
//   B1; threads j<128 reduce 4 partials x 4 gates (16 stride-4B ds_read_b32,
//     conflict-free, issued independently -> one latency exposure),
//     nonlinearities, register-resident c, write hs[j]; B2.
//   xout store issued AFTER B2 so it drains under next FMA phase.
__global__ __launch_bounds__(512, 2) void lstm_scan(const float* __restrict__ Whh,
     const float* __restrict__ P, float* __restrict__ xout){
  __shared__ float hs[128];
  __shared__ float part[4][512];
  const int i  = blockIdx.x;
  const int r  = threadIdx.x;
  const int w  = r >> 6;
  const int l  = r & 63;
  const int kc = w >> 1;               // K-chunk id
  const int rh = w & 1;                // row half
  const int row0 = rh*256 + l*4;       // 4 consecutive rows
  v2f wv[4][16];
  {
    const float* base = Whh + (size_t)i*512*128 + (size_t)row0*128 + kc*32;
    #pragma unroll
    for (int ri=0; ri<4; ri++){
      const v2f* p2 = (const v2f*)(base + ri*128);
      #pragma unroll
      for (int j=0;j<16;j++) wv[ri][j] = p2[j];
    }
  }
  float c = 0.f;
  float hreg = 0.f;
  if (r < 128) hs[r] = 0.f;
  __syncthreads();
  const float* Pi = P + (size_t)i*128*512;
  float* xo = xout + (size_t)i*128*128;
  for (int t=0; t<128; t++){
    // prefetch P for the serial phase (waves 0-1 only); consumed after B1
    float p0=0.f, p1=0.f, p2=0.f, p3=0.f;
    if (r < 128){
      p0 = Pi[t*512 +   0 + r];
      p1 = Pi[t*512 + 128 + r];
      p2 = Pi[t*512 + 256 + r];
      p3 = Pi[t*512 + 384 + r];
    }
    // FMA phase: broadcast-read this wave's 32 h values into registers
    float4 hbuf[8];
    {
      const float4* h4 = ((const float4*)hs) + kc*8;
      #pragma unroll
      for (int j=0;j<8;j++) hbuf[j] = h4[j];
    }
    const v2f* h2 = (const v2f*)hbuf;
    v2f a0 = (v2f)(0.f), a1 = (v2f)(0.f), a2 = (v2f)(0.f), a3 = (v2f)(0.f);
    #pragma unroll
    for (int j=0;j<16;j++){
      v2f hv = h2[j];
      a0 = __builtin_elementwise_fma(wv[0][j], hv, a0);
      a1 = __builtin_elementwise_fma(wv[1][j], hv, a1);
      a2 = __builtin_elementwise_fma(wv[2][j], hv, a2);
      a3 = __builtin_elementwise_fma(wv[3][j], hv, a3);
    }
    float4 pr;
    pr.x = a0.x + a0.y;
    pr.y = a1.x + a1.y;
    pr.z = a2.x + a2.y;
    pr.w = a3.x + a3.y;
    *(float4*)&part[kc][row0] = pr;      // conflict-free b128 (lane stride 16B)
    __syncthreads();                     // B1
    if (r < 128){
      int j = r;
      float s0 = ((part[0][      j] + part[1][      j]) + (part[2][      j] + part[3][      j])) + p0;
      float s1 = ((part[0][128 + j] + part[1][128 + j]) + (part[2][128 + j] + part[3][128 + j])) + p1;
      float s2 = ((part[0][256 + j] + part[1][256 + j]) + (part[2][256 + j] + part[3][256 + j])) + p2;
      float s3 = ((part[0][384 + j] + part[1][384 + j]) + (part[2][384 + j] + part[3][384 + j])) + p3;
      float gi = __builtin_amdgcn_rcpf(1.f + __expf(-s0));
      float gf = __builtin_amdgcn_rcpf(1.f + __expf(-s1));
      float xg = fminf(fmaxf(s2, -15.f), 15.f);
      float eg = __expf(2.f*xg);
      float gg = (eg - 1.f) * __builtin_amdgcn_rcpf(eg + 1.f);
      float go = __builtin_amdgcn_rcpf(1.f + __expf(-s3));
      c = gf*c + gi*gg;
      float xc = fminf(fmaxf(c, -15.f), 15.f);
      float e2 = __expf(2.f*xc);
      float th = (e2 - 1.f) * __builtin_amdgcn_rcpf(e2 + 1.f);
      hreg = go*th;
      hs[j] = hreg;
    }
    __syncthreads();                     // B2
    if (r < 128) xo[t*128 + r] = hreg;   // store drains under next FMA phase
  }
}

// ---------------------------------------------------------------------------
// GAT stage A: ft = f @ W (50000x128 @ 128x128, fp32) + s_src = f @ a_src
// Inner product uses packed-FP32 fma (v_pk_fma_f32) via float2 ext-vectors.
// ---------------------------------------------------------------------------
__global__ __launch_bounds__(256) void gat_transform(const float* __restrict__ f,
    const float* __restrict__ W, const float* __restrict__ aw,
    float* __restrict__ ft, float* __restrict__ s_src){
  __shared__ float Ws[64*128];
  __shared__ float fs[128*36];
  int n0 = blockIdx.x * 32;
  {
    int n = threadIdx.x >> 3, kq = threadIdx.x & 7;
    int gn = n0 + n;
    #pragma unroll
    for (int p=0;p<4;p++){
      int k = kq*16 + p*4;
      float4 v = make_float4(0.f,0.f,0.f,0.f);
      if (gn < N_NODES) v = *(const float4*)(f + (size_t)gn*128 + k);
      fs[(k+0)*36+n] = v.x; fs[(k+1)*36+n] = v.y;
      fs[(k+2)*36+n] = v.z; fs[(k+3)*36+n] = v.w;
    }
  }
  int jg = threadIdx.x & 31, ng = threadIdx.x >> 5;
  v2f A00=(v2f)(0.f), A01=A00, A10=A00, A11=A00;
  v2f A20=A00, A21=A00, A30=A00, A31=A00;
  for (int kk=0; kk<128; kk+=64){
    __syncthreads();
    {
      const float4* W4 = (const float4*)(W + (size_t)kk*128);
      float4* Ws4w = (float4*)Ws;
      for (int idx = threadIdx.x; idx < 2048; idx += 256) Ws4w[idx] = W4[idx];
    }
    __syncthreads();
    const float4* Ws4 = (const float4*)Ws;
    #pragma unroll 4
    for (int k2=0;k2<64;k2++){
      float4 wvv = Ws4[k2*32 + jg];
      v2f wl; wl.x = wvv.x; wl.y = wvv.y;
      v2f wh; wh.x = wvv.z; wh.y = wvv.w;
      float4 fv = *(const float4*)&fs[(kk+k2)*36 + (ng<<2)];
      v2f f0 = (v2f)(fv.x), f1 = (v2f)(fv.y), f2 = (v2f)(fv.z), f3 = (v2f)(fv.w);
      A00 = __builtin_elementwise_fma(wl, f0, A00);
      A01 = __builtin_elementwise_fma(wh, f0, A01);
      A10 = __builtin_elementwise_fma(wl, f1, A10);
      A11 = __builtin_elementwise_fma(wh, f1, A11);
      A20 = __builtin_elementwise_fma(wl, f2, A20);
      A21 = __builtin_elementwise_fma(wh, f2, A21);
      A30 = __builtin_elementwise_fma(wl, f3, A30);
      A31 = __builtin_elementwise_fma(wh, f3, A31);
    }
  }
  int nb = n0 + (ng<<2);
  float4 o0; o0.x=A00.x; o0.y=A00.y; o0.z=A01.x; o0.w=A01.y;
  float4 o1; o1.x=A10.x; o1.y=A10.y; o1.z=A11.x; o1.w=A11.y;
  float4 o2; o2.x=A20.x; o2.y=A20.y; o2.z=A21.x; o2.w=A21.y;
  float4 o3; o3.x=A30.x; o3.y=A30.y; o3.z=A31.x; o3.w=A31.y;
  if (nb+0 < N_NODES) *(float4*)(ft + (size_t)(nb+0)*128 + (jg<<2)) = o0;
  if (nb+1 < N_NODES) *(float4*)(ft + (size_t)(nb+1)*128 + (jg<<2)) = o1;
  if (nb+2 < N_NODES) *(float4*)(ft + (size_t)(nb+2)*128 + (jg<<2)) = o2;
  if (nb+3 < N_NODES) *(float4*)(ft + (size_t)(nb+3)*128 + (jg<<2)) = o3;
  if (threadIdx.x < 32){
    int gn = n0 + threadIdx.x;
    if (gn < N_NODES){
      float s = 0.f;
      for (int k=0;k<128;k++) s += fs[k*36 + threadIdx.x] * aw[k];
      s_src[gn] = s;
    }
  }
}

// ---------------------------------------------------------------------------
// GAT stage B: score[p] = s_src[src_perm[p]] + ef[perm[p]] . a_edge
// ---------------------------------------------------------------------------
__global__ __launch_bounds__(256) void gat_edge_score(const int* __restrict__ perm,
    const int* __restrict__ src_perm, const float* __restrict__ s_src,
    const float* __restrict__ ef, const float* __restrict__ aw,
    float* __restrict__ score){
  int p = blockIdx.x*256 + threadIdx.x;
  if (p >= N_EDGES) return;
  int e = perm[p];
  int s = src_perm[p];
  const float4* A = (const float4*)(aw + 128);
  float4 A0=A[0], A1=A[1], A2=A[2], A3=A[3];
  const float4* ev = (const float4*)(ef + (size_t)e*16);
  float4 v0=ev[0], v1=ev[1], v2=ev[2], v3=ev[3];
  float acc = s_src[s];
  acc += v0.x*A0.x + v0.y*A0.y + v0.z*A0.z + v0.w*A0.w;
  acc += v1.x*A1.x + v1.y*A1.y + v1.z*A1.z + v1.w*A1.w;
  acc += v2.x*A2.x + v2.y*A2.y + v2.z*A2.z + v2.w*A2.w;
  acc += v3.x*A3.x + v3.y*A3.y + v3.z*A3.z + v3.w*A3.w;
  score[p] = acc;
}

// ---------------------------------------------------------------------------
// GAT stage C: per-node softmax + alpha-weighted gather + leaky_relu
// Pass 2 stores exp(score-m) back into score (each p owned by exactly one
// lane of one node-wave -> no hazard), so the serial pass-3 loop is a
// multiply instead of an __expf on the dependency chain.
// ---------------------------------------------------------------------------
__global__ __launch_bounds__(256) void gat_aggregate(const int* __restrict__ row_start,
    const int* __restrict__ src_perm, float* __restrict__ score,
    const float* __restrict__ ft, float* __restrict__ out){
  int lane = threadIdx.x & 63;
  int wv = threadIdx.x >> 6;
  int n = blockIdx.x*4 + wv;
  if (n >= N_NODES) return;
  int s = row_start[n], e = row_start[n+1];
  float m = -1e30f;
  for (int p = s+lane; p < e; p += 64) m = fmaxf(m, score[p]);
  #pragma unroll
  for (int off=32; off; off>>=1) m = fmaxf(m, __shfl_xor(m, off));
  float den = 0.f;
  for (int p = s+lane; p < e; p += 64){
    float ex = __expf(score[p]-m);
    den += ex;
    score[p] = ex;
  }
  #pragma unroll
  for (int off=32; off; off>>=1) den += __shfl_xor(den, off);
  float inv = (den > 0.f) ? 1.f/den : 0.f;
  float a0 = 0.f, a1 = 0.f;
  for (int p = s; p < e; p++){
    float al = score[p]*inv;
    int sp = src_perm[p];
    float2 v = ((const float2*)(ft + (size_t)sp*128))[lane];
    a0 += al*v.x; a1 += al*v.y;
  }
  float2 o;
  o.x = (a0 > 0.f) ? a0 : 0.01f*a0;
  o.y = (a1 > 0.f) ? a1 : 0.01f*a1;
  ((float2*)(out + (size_t)n*128))[lane] = o;
}

// ---------------------------------------------------------------------------
extern "C" void kernel_launch(void* const* d_in, const int* in_sizes, int n_in,
                              void* d_out, int out_size, void* d_ws, size_t ws_size,
                              hipStream_t stream){
  (void)in_sizes; (void)n_in; (void)out_size; (void)ws_size;
  const int*   src     = (const int*)d_in[0] + (size_t)2*N_EDGES;       // j=2 slice
  const int*   dst     = (const int*)d_in[1] + (size_t)2*N_EDGES;
  const float* n_feats = (const float*)d_in[2] + (size_t)2*N_NODES*D;
  const float* e_feats = (const float*)d_in[3] + (size_t)2*N_EDGES*DE;
  const float* W0      = (const float*)d_in[4];
  const float* Wih     = (const float*)d_in[5];
  const float* Whh     = (const float*)d_in[6];
  const float* bih     = (const float*)d_in[7];
  const float* bhh     = (const float*)d_in[8];
  const float* a_w     = (const float*)d_in[9];
  float* out = (float*)d_out;

  char* wsp = (char*)d_ws;
  auto alloc = [&](size_t bytes)->char*{
    char* p = wsp; wsp += (bytes + 255) & ~(size_t)255; return p;
  };
  float* P         = (float*)alloc((size_t)2*128*512*4);
  float* xA        = (float*)alloc((size_t)2*128*128*4);
  float* xB        = (float*)alloc((size_t)2*128*128*4);
  int*   count     = (int*)  alloc((size_t)N_NODES*4);
  int*   bsum      = (int*)  alloc((size_t)NBLK*4);
  int*   boff      = (int*)  alloc((size_t)NBLK*4);
  int*   row_start = (int*)  alloc((size_t)(N_NODES+1)*4);
  int*   cursor    = (int*)  alloc((size_t)N_NODES*4);
  int*   perm      = (int*)  alloc((size_t)N_EDGES*4);
  int*   src_perm  = (int*)  alloc((size_t)N_EDGES*4);
  float* score     = (float*)alloc((size_t)N_EDGES*4);
  float* s_src     = (float*)alloc((size_t)N_NODES*4);
  float* ft        = (float*)alloc((size_t)N_NODES*D*4);
  float* f1        = (float*)alloc((size_t)N_NODES*D*4);

  // CSR build (once; same graph for both layers)
  hipMemsetAsync(count, 0, (size_t)N_NODES*4, stream);
  csr_hist     <<<(N_EDGES+255)/256, 256, 0, stream>>>(dst, count);
  csr_blocksum <<<NBLK, 256, 0, stream>>>(count, bsum);
  csr_scan_bsum<<<1,    256, 0, stream>>>(bsum, boff);
  csr_downsweep<<<NBLK, 256, 0, stream>>>(count, boff, row_start, cursor);
  csr_scatter  <<<(N_EDGES+255)/256, 256, 0, stream>>>(src, dst, cursor, perm, src_perm);

  // LSTM: 3 applications, both layers batched per launch; final W lands in xA
  const float* xi = W0;
  float* xo = xA;
  for (int app=0; app<3; app++){
    lstm_pre <<<256, 512, 0, stream>>>(Wih, bih, bhh, xi, P);
    lstm_scan<<<2,   512, 0, stream>>>(Whh, P, xo);
    xi = xo;
    xo = (app==0) ? xB : xA;
  }
  const float* Wfin = xA;   // app0->xA, app1->xB, app2->xA

  // Two GAT layers on graph j=2 (feats[0],feats[1] are dead w.r.t. output)
  const float* fin = n_feats;
  for (int l=0; l<2; l++){
    float* outl = (l==0) ? f1 : out;
    gat_transform <<<(N_NODES+31)/32, 256, 0, stream>>>(fin, Wfin + (size_t)l*16384,
                                                        a_w + (size_t)l*272, ft, s_src);
    gat_edge_score<<<(N_EDGES+255)/256, 256, 0, stream>>>(perm, src_perm, s_src,
                                                          e_feats, a_w + (size_t)l*272, score);
    gat_aggregate <<<N_NODES/4, 256, 0, stream>>>(row_start, src_perm, score, ft, outl);
    fin = f1;
  }
}